// Round 2
// 936.790 us; speedup vs baseline: 1.1819x; 1.1819x over previous
//
#include <hip/hip_runtime.h>
#include <hip/hip_bf16.h>
#include <cstdint>
#include <cstddef>

#define B_  2
#define S_  2048
#define D_  1024
#define H_  16
#define DK_ 64

typedef _Float16 half8 __attribute__((ext_vector_type(8)));
typedef _Float16 half4v __attribute__((ext_vector_type(4)));
typedef float floatx4 __attribute__((ext_vector_type(4)));

#define AS1 __attribute__((address_space(1)))
#define AS3 __attribute__((address_space(3)))

__device__ __forceinline__ half8 ld_half8(const _Float16* p) {
    return *reinterpret_cast<const half8*>(p);
}

#define MFMA16(a, b, c) __builtin_amdgcn_mfma_f32_16x16x32_f16((a), (b), (c), 0, 0, 0)

// ---------------- prep: fp32 -> fp16 (vectorized) ----------------
__global__ void k_f32_to_f16(const float* __restrict__ src, _Float16* __restrict__ dst, int n4) {
    int i = blockIdx.x * blockDim.x + threadIdx.x;
    if (i >= n4) return;
    float4 v = reinterpret_cast<const float4*>(src)[i];
    half4v o;
    o[0] = (_Float16)v.x; o[1] = (_Float16)v.y; o[2] = (_Float16)v.z; o[3] = (_Float16)v.w;
    *reinterpret_cast<half4v*>(dst + 4 * (size_t)i) = o;
}

// ---------------- prep: weight transpose fp32 [k][n] -> fp16 [n][k] ----------------
__global__ void k_wtrans(const float* __restrict__ W0, const float* __restrict__ W1,
                         const float* __restrict__ W2, const float* __restrict__ W3,
                         _Float16* __restrict__ T0, _Float16* __restrict__ T1,
                         _Float16* __restrict__ T2, _Float16* __restrict__ T3) {
    const float* W = (blockIdx.z == 0) ? W0 : (blockIdx.z == 1) ? W1 : (blockIdx.z == 2) ? W2 : W3;
    _Float16*    T = (blockIdx.z == 0) ? T0 : (blockIdx.z == 1) ? T1 : (blockIdx.z == 2) ? T2 : T3;
    __shared__ float t[32][33];
    int x = blockIdx.x * 32 + threadIdx.x;
    #pragma unroll
    for (int yy = threadIdx.y; yy < 32; yy += 8) {
        t[yy][threadIdx.x] = W[(size_t)(blockIdx.y * 32 + yy) * D_ + x];
    }
    __syncthreads();
    #pragma unroll
    for (int yy = threadIdx.y; yy < 32; yy += 8) {
        T[(size_t)(blockIdx.x * 32 + yy) * D_ + blockIdx.y * 32 + threadIdx.x] =
            (_Float16)t[threadIdx.x][yy];
    }
}

// ---------------- fused QKV projection GEMM (m97 structure: 128x128, BK=32, LDS-staged) ----------------
// X [4096,1024] fp16 (row-major), WT [n][k] fp16. z selects q/k/v.
// q,k stored [B,H,S,DK]; v stored transposed [B,H,DK,S]. q pre-scaled by 1/8.
__launch_bounds__(256)
__global__ void k_qkv_gemm(const _Float16* __restrict__ Xq, const _Float16* __restrict__ Xk,
                           const _Float16* __restrict__ Xv,
                           const _Float16* __restrict__ WqT, const _Float16* __restrict__ WkT,
                           const _Float16* __restrict__ WvT,
                           const float* __restrict__ bq, const float* __restrict__ bk,
                           const float* __restrict__ bv,
                           _Float16* __restrict__ qo, _Float16* __restrict__ ko,
                           _Float16* __restrict__ vTo) {
    __shared__ __align__(16) _Float16 As[128 * 32];
    __shared__ __align__(16) _Float16 Bs[128 * 32];

    const int z = blockIdx.z;
    const _Float16* X    = (z == 0) ? Xq  : (z == 1) ? Xk  : Xv;
    const _Float16* WT   = (z == 0) ? WqT : (z == 1) ? WkT : WvT;
    const float*    bias = (z == 0) ? bq  : (z == 1) ? bk  : bv;

    const int tid = threadIdx.x;
    const int lane = tid & 63, wave = tid >> 6;
    const int lr = lane & 15, q4 = lane >> 4;
    const int wr = wave >> 1, wc = wave & 1;   // wave -> 64x64 quadrant
    const int m0 = blockIdx.y * 128;
    const int n0 = blockIdx.x * 128;

    // staging: tile = 128 rows x 32 halves = 512 chunks of 16B; chunk c -> row c>>2, k-off (c&3)*8
    const int c0 = tid, c1 = tid + 256;
    const _Float16* aS0 = X  + (size_t)(m0 + (c0 >> 2)) * D_ + (c0 & 3) * 8;
    const _Float16* aS1 = X  + (size_t)(m0 + (c1 >> 2)) * D_ + (c1 & 3) * 8;
    const _Float16* bS0 = WT + (size_t)(n0 + (c0 >> 2)) * D_ + (c0 & 3) * 8;
    const _Float16* bS1 = WT + (size_t)(n0 + (c1 >> 2)) * D_ + (c1 & 3) * 8;
    _Float16* aD0 = As + c0 * 8;  _Float16* aD1 = As + c1 * 8;
    _Float16* bD0 = Bs + c0 * 8;  _Float16* bD1 = Bs + c1 * 8;

    floatx4 acc[4][4];
    #pragma unroll
    for (int mt = 0; mt < 4; mt++)
        #pragma unroll
        for (int nt = 0; nt < 4; nt++)
            acc[mt][nt] = (floatx4){0.f, 0.f, 0.f, 0.f};

    for (int k0 = 0; k0 < D_; k0 += 32) {
        __builtin_amdgcn_global_load_lds((const AS1 void*)(aS0 + k0), (AS3 void*)aD0, 16, 0, 0);
        __builtin_amdgcn_global_load_lds((const AS1 void*)(aS1 + k0), (AS3 void*)aD1, 16, 0, 0);
        __builtin_amdgcn_global_load_lds((const AS1 void*)(bS0 + k0), (AS3 void*)bD0, 16, 0, 0);
        __builtin_amdgcn_global_load_lds((const AS1 void*)(bS1 + k0), (AS3 void*)bD1, 16, 0, 0);
        __syncthreads();  // drains vmcnt -> staged data visible
        half8 af[4], bf[4];
        #pragma unroll
        for (int mt = 0; mt < 4; mt++)
            af[mt] = *reinterpret_cast<const half8*>(As + (size_t)(wr * 64 + mt * 16 + lr) * 32 + q4 * 8);
        #pragma unroll
        for (int nt = 0; nt < 4; nt++)
            bf[nt] = *reinterpret_cast<const half8*>(Bs + (size_t)(wc * 64 + nt * 16 + lr) * 32 + q4 * 8);
        #pragma unroll
        for (int mt = 0; mt < 4; mt++)
            #pragma unroll
            for (int nt = 0; nt < 4; nt++)
                acc[mt][nt] = MFMA16(af[mt], bf[nt], acc[mt][nt]);
        __syncthreads();  // WAR: protect LDS for next k0
    }

    #pragma unroll
    for (int mt = 0; mt < 4; mt++) {
        #pragma unroll
        for (int nt = 0; nt < 4; nt++) {
            int gn = n0 + wc * 64 + nt * 16 + lr;
            float bval = bias[gn];
            int h = gn >> 6, dk = gn & 63;
            #pragma unroll
            for (int r = 0; r < 4; r++) {
                int gm = m0 + wr * 64 + mt * 16 + q4 * 4 + r;
                float val = acc[mt][nt][r] + bval;
                int b = gm >> 11, s = gm & (S_ - 1);
                if (z == 0) {
                    qo[(((size_t)b * H_ + h) * S_ + s) * DK_ + dk] = (_Float16)(val * 0.125f);
                } else if (z == 1) {
                    ko[(((size_t)b * H_ + h) * S_ + s) * DK_ + dk] = (_Float16)val;
                } else {
                    vTo[(((size_t)b * H_ + h) * DK_ + dk) * S_ + s] = (_Float16)val;
                }
            }
        }
    }
}

// ---------------- fused attention: scores + softmax + attn write + PV ----------------
// Swapped-operand scores: s = mfma(K, Q) -> lane holds 4 CONSECUTIVE j of ONE q-row
//   => float4 attn stores, scalar row-sum per lane.
// Block = 4 waves: 2 q-subtiles (16 rows) x 2 j-halves (S/2). Grid (S/32, B*H) = 8192 waves.
__launch_bounds__(256)
__global__ void k_attn(const _Float16* __restrict__ q, const _Float16* __restrict__ k,
                       const _Float16* __restrict__ vT,
                       float* __restrict__ attn, _Float16* __restrict__ oh) {
    __shared__ __align__(16) _Float16 plds[4][16][40];  // per-wave P transpose for PV
    __shared__ float sums[2][2][16];                    // [qt][jh][row]
    __shared__ __align__(16) float ocomb[2][64][16];    // [qt][lane][nt*4+r] partial PV

    const int bh = blockIdx.y;
    const int lane = threadIdx.x & 63, wave = threadIdx.x >> 6;
    const int qt = wave >> 1, jh = wave & 1;
    const int lr = lane & 15, q4 = lane >> 4;
    const int i0 = blockIdx.x * 32 + qt * 16;
    const int jbase = jh * (S_ / 2);

    const _Float16* qb = q + (size_t)bh * S_ * DK_;
    const _Float16* kb = k + (size_t)bh * S_ * DK_;
    const _Float16* vb = vT + (size_t)bh * DK_ * S_;

    // Q as B-fragment: col=lr -> q-row i0+lr, k-slices q4*8 (loaded once)
    half8 qf0 = ld_half8(qb + (size_t)(i0 + lr) * DK_ + q4 * 8);
    half8 qf1 = ld_half8(qb + (size_t)(i0 + lr) * DK_ + 32 + q4 * 8);

    // ---- pass A: partial row sums of exp(scores) over this wave's j-half ----
    float psum = 0.f;
    for (int jc = jbase; jc < jbase + S_ / 2; jc += 16) {
        const _Float16* krow = kb + (size_t)(jc + lr) * DK_ + q4 * 8;
        half8 kf0 = ld_half8(krow);
        half8 kf1 = ld_half8(krow + 32);
        floatx4 s = {0.f, 0.f, 0.f, 0.f};
        s = MFMA16(kf0, qf0, s);   // C: col=lr -> q-row, row=q4*4+r -> j
        s = MFMA16(kf1, qf1, s);
        psum += __expf(s[0]) + __expf(s[1]) + __expf(s[2]) + __expf(s[3]);
    }
    psum += __shfl_xor(psum, 16);  // combine q4 bit0
    psum += __shfl_xor(psum, 32);  // combine q4 bit1
    if (q4 == 0) sums[qt][jh][lr] = psum;
    __syncthreads();
    const float inv = 1.0f / (sums[qt][0][lr] + sums[qt][1][lr]);

    // ---- pass B: recompute scores, write normalized attn (float4 NT), accumulate partial PV ----
    floatx4 oacc[4];
    #pragma unroll
    for (int nt = 0; nt < 4; nt++) oacc[nt] = (floatx4){0.f, 0.f, 0.f, 0.f};
    float* arow = attn + (size_t)bh * S_ * S_ + (size_t)(i0 + lr) * S_;

    for (int j0 = jbase; j0 < jbase + S_ / 2; j0 += 32) {
        #pragma unroll
        for (int c = 0; c < 2; c++) {
            const int jc = j0 + c * 16;
            const _Float16* krow = kb + (size_t)(jc + lr) * DK_ + q4 * 8;
            half8 kf0 = ld_half8(krow);
            half8 kf1 = ld_half8(krow + 32);
            floatx4 s = {0.f, 0.f, 0.f, 0.f};
            s = MFMA16(kf0, qf0, s);
            s = MFMA16(kf1, qf1, s);
            floatx4 p;
            p[0] = __expf(s[0]) * inv;
            p[1] = __expf(s[1]) * inv;
            p[2] = __expf(s[2]) * inv;
            p[3] = __expf(s[3]) * inv;
            // 4 consecutive columns of q-row (i0+lr): one 16B nontemporal store
            __builtin_nontemporal_store(p, reinterpret_cast<floatx4*>(arow + jc + q4 * 4));
            half4v ph;
            ph[0] = (_Float16)p[0]; ph[1] = (_Float16)p[1];
            ph[2] = (_Float16)p[2]; ph[3] = (_Float16)p[3];
            // P in [q-row][j] layout for PV A-fragment
            *reinterpret_cast<half4v*>(&plds[wave][lr][c * 16 + q4 * 4]) = ph;
        }
        __threadfence_block();  // order wave-local LDS write -> read
        half8 pa = *reinterpret_cast<const half8*>(&plds[wave][lr][q4 * 8]);
        #pragma unroll
        for (int nt = 0; nt < 4; nt++) {
            half8 vv = ld_half8(vb + (size_t)(nt * 16 + lr) * S_ + j0 + q4 * 8);
            oacc[nt] = MFMA16(pa, vv, oacc[nt]);
        }
    }

    // ---- combine partial PV across the two j-half waves, write out_heads ----
    if (jh == 1) {
        #pragma unroll
        for (int nt = 0; nt < 4; nt++)
            *reinterpret_cast<floatx4*>(&ocomb[qt][lane][nt * 4]) = oacc[nt];
    }
    __syncthreads();
    if (jh == 0) {
        const int b = bh >> 4, h = bh & 15;
        #pragma unroll
        for (int nt = 0; nt < 4; nt++) {
            oacc[nt] += *reinterpret_cast<const floatx4*>(&ocomb[qt][lane][nt * 4]);
            #pragma unroll
            for (int r = 0; r < 4; r++) {
                oh[((size_t)b * S_ + i0 + q4 * 4 + r) * D_ + h * DK_ + nt * 16 + lr] =
                    (_Float16)oacc[nt][r];
            }
        }
    }
}

// ---------------- output projection GEMM (same m97 structure): out = oh @ Wo + bo (fp32) ----------------
__launch_bounds__(256)
__global__ void k_out_gemm(const _Float16* __restrict__ X, const _Float16* __restrict__ WT,
                           const float* __restrict__ bias, float* __restrict__ out) {
    __shared__ __align__(16) _Float16 As[128 * 32];
    __shared__ __align__(16) _Float16 Bs[128 * 32];

    const int tid = threadIdx.x;
    const int lane = tid & 63, wave = tid >> 6;
    const int lr = lane & 15, q4 = lane >> 4;
    const int wr = wave >> 1, wc = wave & 1;
    const int m0 = blockIdx.y * 128;
    const int n0 = blockIdx.x * 128;

    const int c0 = tid, c1 = tid + 256;
    const _Float16* aS0 = X  + (size_t)(m0 + (c0 >> 2)) * D_ + (c0 & 3) * 8;
    const _Float16* aS1 = X  + (size_t)(m0 + (c1 >> 2)) * D_ + (c1 & 3) * 8;
    const _Float16* bS0 = WT + (size_t)(n0 + (c0 >> 2)) * D_ + (c0 & 3) * 8;
    const _Float16* bS1 = WT + (size_t)(n0 + (c1 >> 2)) * D_ + (c1 & 3) * 8;
    _Float16* aD0 = As + c0 * 8;  _Float16* aD1 = As + c1 * 8;
    _Float16* bD0 = Bs + c0 * 8;  _Float16* bD1 = Bs + c1 * 8;

    floatx4 acc[4][4];
    #pragma unroll
    for (int mt = 0; mt < 4; mt++)
        #pragma unroll
        for (int nt = 0; nt < 4; nt++)
            acc[mt][nt] = (floatx4){0.f, 0.f, 0.f, 0.f};

    for (int k0 = 0; k0 < D_; k0 += 32) {
        __builtin_amdgcn_global_load_lds((const AS1 void*)(aS0 + k0), (AS3 void*)aD0, 16, 0, 0);
        __builtin_amdgcn_global_load_lds((const AS1 void*)(aS1 + k0), (AS3 void*)aD1, 16, 0, 0);
        __builtin_amdgcn_global_load_lds((const AS1 void*)(bS0 + k0), (AS3 void*)bD0, 16, 0, 0);
        __builtin_amdgcn_global_load_lds((const AS1 void*)(bS1 + k0), (AS3 void*)bD1, 16, 0, 0);
        __syncthreads();
        half8 af[4], bf[4];
        #pragma unroll
        for (int mt = 0; mt < 4; mt++)
            af[mt] = *reinterpret_cast<const half8*>(As + (size_t)(wr * 64 + mt * 16 + lr) * 32 + q4 * 8);
        #pragma unroll
        for (int nt = 0; nt < 4; nt++)
            bf[nt] = *reinterpret_cast<const half8*>(Bs + (size_t)(wc * 64 + nt * 16 + lr) * 32 + q4 * 8);
        #pragma unroll
        for (int mt = 0; mt < 4; mt++)
            #pragma unroll
            for (int nt = 0; nt < 4; nt++)
                acc[mt][nt] = MFMA16(af[mt], bf[nt], acc[mt][nt]);
        __syncthreads();
    }

    #pragma unroll
    for (int mt = 0; mt < 4; mt++) {
        #pragma unroll
        for (int nt = 0; nt < 4; nt++) {
            int gn = n0 + wc * 64 + nt * 16 + lr;
            float bval = bias[gn];
            #pragma unroll
            for (int r = 0; r < 4; r++) {
                int gm = m0 + wr * 64 + mt * 16 + q4 * 4 + r;
                out[(size_t)gm * D_ + gn] = acc[mt][nt][r] + bval;
            }
        }
    }
}

extern "C" void kernel_launch(void* const* d_in, const int* in_sizes, int n_in,
                              void* d_out, int out_size, void* d_ws, size_t ws_size,
                              hipStream_t stream) {
    const float* Q_in = (const float*)d_in[0];
    const float* K_in = (const float*)d_in[1];
    const float* V_in = (const float*)d_in[2];
    const float* Wq = (const float*)d_in[3];
    const float* bq = (const float*)d_in[4];
    const float* Wk = (const float*)d_in[5];
    const float* bk = (const float*)d_in[6];
    const float* Wv = (const float*)d_in[7];
    const float* bv = (const float*)d_in[8];
    const float* Wo = (const float*)d_in[9];
    const float* bo = (const float*)d_in[10];

    const size_t NEL = (size_t)B_ * S_ * D_;  // 4M
    _Float16* Xhq = (_Float16*)d_ws;
    _Float16* Xhk = Xhq + NEL;
    _Float16* Xhv = Xhk + NEL;
    _Float16* WqT = Xhv + NEL;
    _Float16* WkT = WqT + (size_t)D_ * D_;
    _Float16* WvT = WkT + (size_t)D_ * D_;
    _Float16* WoT = WvT + (size_t)D_ * D_;
    _Float16* qh  = WoT + (size_t)D_ * D_;
    _Float16* kh  = qh + NEL;
    _Float16* vTh = kh + NEL;
    _Float16* ohh = vTh + NEL;  // out_heads [B,S,D] fp16
    // total ws use: 32M halves = 64 MB

    float* out  = (float*)d_out;
    float* attn = out + NEL;  // attn region starts after out [B,S,D]

    const int n4 = (int)(NEL / 4);
    dim3 cvtg((n4 + 255) / 256);
    k_f32_to_f16<<<cvtg, 256, 0, stream>>>(Q_in, Xhq, n4);
    k_f32_to_f16<<<cvtg, 256, 0, stream>>>(K_in, Xhk, n4);
    k_f32_to_f16<<<cvtg, 256, 0, stream>>>(V_in, Xhv, n4);

    k_wtrans<<<dim3(32, 32, 4), dim3(32, 8), 0, stream>>>(Wq, Wk, Wv, Wo, WqT, WkT, WvT, WoT);

    k_qkv_gemm<<<dim3(D_ / 128, (B_ * S_) / 128, 3), 256, 0, stream>>>(
        Xhq, Xhk, Xhv, WqT, WkT, WvT, bq, bk, bv, qh, kh, vTh);

    k_attn<<<dim3(S_ / 32, B_ * H_), 256, 0, stream>>>(qh, kh, vTh, attn, ohh);

    k_out_gemm<<<dim3(D_ / 128, (B_ * S_) / 128), 256, 0, stream>>>(ohh, WoT, bo, out);
}

// Round 3
// 835.985 us; speedup vs baseline: 1.3244x; 1.1206x over previous
//
#include <hip/hip_runtime.h>
#include <hip/hip_bf16.h>
#include <cstdint>
#include <cstddef>

#define B_  2
#define S_  2048
#define D_  1024
#define H_  16
#define DK_ 64

typedef _Float16 half8 __attribute__((ext_vector_type(8)));
typedef _Float16 half4v __attribute__((ext_vector_type(4)));
typedef float floatx4 __attribute__((ext_vector_type(4)));

#define AS1 __attribute__((address_space(1)))
#define AS3 __attribute__((address_space(3)))

__device__ __forceinline__ half8 ld_half8(const _Float16* p) {
    return *reinterpret_cast<const half8*>(p);
}

#define MFMA16(a, b, c) __builtin_amdgcn_mfma_f32_16x16x32_f16((a), (b), (c), 0, 0, 0)

// ---------------- prep: fp32 -> fp16 (vectorized) ----------------
__global__ void k_f32_to_f16(const float* __restrict__ src, _Float16* __restrict__ dst, int n4) {
    int i = blockIdx.x * blockDim.x + threadIdx.x;
    if (i >= n4) return;
    float4 v = reinterpret_cast<const float4*>(src)[i];
    half4v o;
    o[0] = (_Float16)v.x; o[1] = (_Float16)v.y; o[2] = (_Float16)v.z; o[3] = (_Float16)v.w;
    *reinterpret_cast<half4v*>(dst + 4 * (size_t)i) = o;
}

// ---------------- prep: weight transpose fp32 [k][n] -> fp16 [n][k] ----------------
__global__ void k_wtrans(const float* __restrict__ W0, const float* __restrict__ W1,
                         const float* __restrict__ W2, const float* __restrict__ W3,
                         _Float16* __restrict__ T0, _Float16* __restrict__ T1,
                         _Float16* __restrict__ T2, _Float16* __restrict__ T3) {
    const float* W = (blockIdx.z == 0) ? W0 : (blockIdx.z == 1) ? W1 : (blockIdx.z == 2) ? W2 : W3;
    _Float16*    T = (blockIdx.z == 0) ? T0 : (blockIdx.z == 1) ? T1 : (blockIdx.z == 2) ? T2 : T3;
    __shared__ float t[32][33];
    int x = blockIdx.x * 32 + threadIdx.x;
    #pragma unroll
    for (int yy = threadIdx.y; yy < 32; yy += 8) {
        t[yy][threadIdx.x] = W[(size_t)(blockIdx.y * 32 + yy) * D_ + x];
    }
    __syncthreads();
    #pragma unroll
    for (int yy = threadIdx.y; yy < 32; yy += 8) {
        T[(size_t)(blockIdx.x * 32 + yy) * D_ + blockIdx.y * 32 + threadIdx.x] =
            (_Float16)t[threadIdx.x][yy];
    }
}

// ---------------- fused QKV projection GEMM (m97 structure: 128x128, BK=32, LDS-staged) ----------------
__launch_bounds__(256)
__global__ void k_qkv_gemm(const _Float16* __restrict__ Xq, const _Float16* __restrict__ Xk,
                           const _Float16* __restrict__ Xv,
                           const _Float16* __restrict__ WqT, const _Float16* __restrict__ WkT,
                           const _Float16* __restrict__ WvT,
                           const float* __restrict__ bq, const float* __restrict__ bk,
                           const float* __restrict__ bv,
                           _Float16* __restrict__ qo, _Float16* __restrict__ ko,
                           _Float16* __restrict__ vTo) {
    __shared__ __align__(16) _Float16 As[128 * 32];
    __shared__ __align__(16) _Float16 Bs[128 * 32];

    const int z = blockIdx.z;
    const _Float16* X    = (z == 0) ? Xq  : (z == 1) ? Xk  : Xv;
    const _Float16* WT   = (z == 0) ? WqT : (z == 1) ? WkT : WvT;
    const float*    bias = (z == 0) ? bq  : (z == 1) ? bk  : bv;

    const int tid = threadIdx.x;
    const int lane = tid & 63, wave = tid >> 6;
    const int lr = lane & 15, q4 = lane >> 4;
    const int wr = wave >> 1, wc = wave & 1;   // wave -> 64x64 quadrant
    const int m0 = blockIdx.y * 128;
    const int n0 = blockIdx.x * 128;

    const int c0 = tid, c1 = tid + 256;
    const _Float16* aS0 = X  + (size_t)(m0 + (c0 >> 2)) * D_ + (c0 & 3) * 8;
    const _Float16* aS1 = X  + (size_t)(m0 + (c1 >> 2)) * D_ + (c1 & 3) * 8;
    const _Float16* bS0 = WT + (size_t)(n0 + (c0 >> 2)) * D_ + (c0 & 3) * 8;
    const _Float16* bS1 = WT + (size_t)(n0 + (c1 >> 2)) * D_ + (c1 & 3) * 8;
    _Float16* aD0 = As + c0 * 8;  _Float16* aD1 = As + c1 * 8;
    _Float16* bD0 = Bs + c0 * 8;  _Float16* bD1 = Bs + c1 * 8;

    floatx4 acc[4][4];
    #pragma unroll
    for (int mt = 0; mt < 4; mt++)
        #pragma unroll
        for (int nt = 0; nt < 4; nt++)
            acc[mt][nt] = (floatx4){0.f, 0.f, 0.f, 0.f};

    for (int k0 = 0; k0 < D_; k0 += 32) {
        __builtin_amdgcn_global_load_lds((const AS1 void*)(aS0 + k0), (AS3 void*)aD0, 16, 0, 0);
        __builtin_amdgcn_global_load_lds((const AS1 void*)(aS1 + k0), (AS3 void*)aD1, 16, 0, 0);
        __builtin_amdgcn_global_load_lds((const AS1 void*)(bS0 + k0), (AS3 void*)bD0, 16, 0, 0);
        __builtin_amdgcn_global_load_lds((const AS1 void*)(bS1 + k0), (AS3 void*)bD1, 16, 0, 0);
        __syncthreads();
        half8 af[4], bf[4];
        #pragma unroll
        for (int mt = 0; mt < 4; mt++)
            af[mt] = *reinterpret_cast<const half8*>(As + (size_t)(wr * 64 + mt * 16 + lr) * 32 + q4 * 8);
        #pragma unroll
        for (int nt = 0; nt < 4; nt++)
            bf[nt] = *reinterpret_cast<const half8*>(Bs + (size_t)(wc * 64 + nt * 16 + lr) * 32 + q4 * 8);
        #pragma unroll
        for (int mt = 0; mt < 4; mt++)
            #pragma unroll
            for (int nt = 0; nt < 4; nt++)
                acc[mt][nt] = MFMA16(af[mt], bf[nt], acc[mt][nt]);
        __syncthreads();
    }

    #pragma unroll
    for (int mt = 0; mt < 4; mt++) {
        #pragma unroll
        for (int nt = 0; nt < 4; nt++) {
            int gn = n0 + wc * 64 + nt * 16 + lr;
            float bval = bias[gn];
            int h = gn >> 6, dk = gn & 63;
            #pragma unroll
            for (int r = 0; r < 4; r++) {
                int gm = m0 + wr * 64 + mt * 16 + q4 * 4 + r;
                float val = acc[mt][nt][r] + bval;
                int b = gm >> 11, s = gm & (S_ - 1);
                if (z == 0) {
                    qo[(((size_t)b * H_ + h) * S_ + s) * DK_ + dk] = (_Float16)(val * 0.125f);
                } else if (z == 1) {
                    ko[(((size_t)b * H_ + h) * S_ + s) * DK_ + dk] = (_Float16)val;
                } else {
                    vTo[(((size_t)b * H_ + h) * DK_ + dk) * S_ + s] = (_Float16)val;
                }
            }
        }
    }
}

// ---------------- fused attention: single-pass, P~ cached in LDS ----------------
// Block = 16 q-rows x full S, 4 waves (each owns a 512-wide j-chunk for QK^T).
// Phase 1: s = mfma(K,Q) swapped -> exp -> fp16 P~ to LDS (XOR-swizzled) + partial row sums.
// Phase 2: inv[16] = 1/rowsum. Phase 3 (per wave): coalesced NT attn stores (rows w*4..w*4+3),
// then PV from LDS P~ (wave w owns dk quarter), scale by inv at end.
__launch_bounds__(256)
__global__ void k_attn(const _Float16* __restrict__ q, const _Float16* __restrict__ k,
                       const _Float16* __restrict__ vT,
                       float* __restrict__ attn, _Float16* __restrict__ oh) {
    extern __shared__ _Float16 smem[];
    _Float16* P   = smem;                          // [16][2048] fp16, XOR-swizzled (64 KB)
    float* psums  = (float*)(smem + 16 * 2048);    // [4][16]
    float* invs   = psums + 64;                    // [16]

    // XCD-locality remap: co-locate the 128 blocks of one (b,h) on one XCD's L2.
    const int rawid = blockIdx.y * gridDim.x + blockIdx.x;   // 0..4095, x-fastest dispatch
    const int v = (rawid & 7) * 512 + (rawid >> 3);          // bijective: 8 XCD groups of 512
    const int bh = v >> 7;                                   // 0..31
    const int i0 = (v & 127) * 16;                           // q-row tile base

    const int lane = threadIdx.x & 63, w = threadIdx.x >> 6;
    const int lr = lane & 15, q4 = lane >> 4;
    const int swz = (lr & 7) << 3;   // XOR in half-units (16B granules)

    const _Float16* qb = q + (size_t)bh * S_ * DK_;
    const _Float16* kb = k + (size_t)bh * S_ * DK_;
    const _Float16* vb = vT + (size_t)bh * DK_ * S_;

    // Q as B-fragment: lane lr <-> q-row i0+lr (q pre-scaled by 1/8)
    half8 qf0 = ld_half8(qb + (size_t)(i0 + lr) * DK_ + q4 * 8);
    half8 qf1 = ld_half8(qb + (size_t)(i0 + lr) * DK_ + 32 + q4 * 8);

    // ---- phase 1: scores + exp once, P~ -> LDS, partial row sums ----
    float psum = 0.f;
    const int jc0 = w * 512;
    #pragma unroll 2
    for (int jc = jc0; jc < jc0 + 512; jc += 16) {
        const _Float16* krow = kb + (size_t)(jc + lr) * DK_ + q4 * 8;
        half8 kf0 = ld_half8(krow);
        half8 kf1 = ld_half8(krow + 32);
        floatx4 s = {0.f, 0.f, 0.f, 0.f};
        s = MFMA16(kf0, qf0, s);   // D: col=lr -> q-row, row=q4*4+r -> j
        s = MFMA16(kf1, qf1, s);
        float e0 = __expf(s[0]), e1 = __expf(s[1]), e2 = __expf(s[2]), e3 = __expf(s[3]);
        psum += (e0 + e1) + (e2 + e3);
        half4v ph;
        ph[0] = (_Float16)e0; ph[1] = (_Float16)e1;
        ph[2] = (_Float16)e2; ph[3] = (_Float16)e3;
        *reinterpret_cast<half4v*>(&P[(lr * 2048 + jc + q4 * 4) ^ swz]) = ph;
    }
    psum += __shfl_xor(psum, 16);
    psum += __shfl_xor(psum, 32);
    if (q4 == 0) psums[w * 16 + lr] = psum;
    __syncthreads();

    // ---- phase 2: full row sums -> inv ----
    if (threadIdx.x < 16)
        invs[threadIdx.x] = 1.0f / (psums[threadIdx.x] + psums[16 + threadIdx.x] +
                                    psums[32 + threadIdx.x] + psums[48 + threadIdx.x]);
    __syncthreads();

    // ---- phase 3a: coalesced attn stores (wave w -> rows w*4 + q4) ----
    {
        const int r = w * 4 + q4;
        const float myinv = invs[r];
        const int rsw = (r & 7) << 3;
        float* arow = attn + (size_t)bh * S_ * S_ + (size_t)(i0 + r) * S_;
        #pragma unroll 4
        for (int i = 0; i < 32; i++) {
            int col = i * 64 + lr * 4;
            half4v ph = *reinterpret_cast<const half4v*>(&P[(r * 2048 + col) ^ rsw]);
            floatx4 pv;
            pv[0] = (float)ph[0] * myinv; pv[1] = (float)ph[1] * myinv;
            pv[2] = (float)ph[2] * myinv; pv[3] = (float)ph[3] * myinv;
            __builtin_nontemporal_store(pv, reinterpret_cast<floatx4*>(arow + col));
        }
    }

    // ---- phase 3b: PV from LDS P~ (wave w -> dk quarter w*16..w*16+15) ----
    floatx4 oacc = {0.f, 0.f, 0.f, 0.f};
    const _Float16* vrow = vb + (size_t)(w * 16 + lr) * S_ + q4 * 8;
    #pragma unroll 4
    for (int j0 = 0; j0 < S_; j0 += 32) {
        half8 pa = *reinterpret_cast<const half8*>(&P[(lr * 2048 + j0 + q4 * 8) ^ swz]);
        half8 vv = ld_half8(vrow + j0);
        oacc = MFMA16(pa, vv, oacc);   // D: m=q4*4+r -> q-row, n=lr -> dk
    }
    const int b = bh >> 4, h = bh & 15;
    #pragma unroll
    for (int r = 0; r < 4; r++) {
        float val = oacc[r] * invs[q4 * 4 + r];
        oh[((size_t)b * S_ + i0 + q4 * 4 + r) * D_ + h * DK_ + w * 16 + lr] = (_Float16)val;
    }
}

// ---------------- output projection GEMM (m97 structure): out = oh @ Wo + bo (fp32) ----------------
__launch_bounds__(256)
__global__ void k_out_gemm(const _Float16* __restrict__ X, const _Float16* __restrict__ WT,
                           const float* __restrict__ bias, float* __restrict__ out) {
    __shared__ __align__(16) _Float16 As[128 * 32];
    __shared__ __align__(16) _Float16 Bs[128 * 32];

    const int tid = threadIdx.x;
    const int lane = tid & 63, wave = tid >> 6;
    const int lr = lane & 15, q4 = lane >> 4;
    const int wr = wave >> 1, wc = wave & 1;
    const int m0 = blockIdx.y * 128;
    const int n0 = blockIdx.x * 128;

    const int c0 = tid, c1 = tid + 256;
    const _Float16* aS0 = X  + (size_t)(m0 + (c0 >> 2)) * D_ + (c0 & 3) * 8;
    const _Float16* aS1 = X  + (size_t)(m0 + (c1 >> 2)) * D_ + (c1 & 3) * 8;
    const _Float16* bS0 = WT + (size_t)(n0 + (c0 >> 2)) * D_ + (c0 & 3) * 8;
    const _Float16* bS1 = WT + (size_t)(n0 + (c1 >> 2)) * D_ + (c1 & 3) * 8;
    _Float16* aD0 = As + c0 * 8;  _Float16* aD1 = As + c1 * 8;
    _Float16* bD0 = Bs + c0 * 8;  _Float16* bD1 = Bs + c1 * 8;

    floatx4 acc[4][4];
    #pragma unroll
    for (int mt = 0; mt < 4; mt++)
        #pragma unroll
        for (int nt = 0; nt < 4; nt++)
            acc[mt][nt] = (floatx4){0.f, 0.f, 0.f, 0.f};

    for (int k0 = 0; k0 < D_; k0 += 32) {
        __builtin_amdgcn_global_load_lds((const AS1 void*)(aS0 + k0), (AS3 void*)aD0, 16, 0, 0);
        __builtin_amdgcn_global_load_lds((const AS1 void*)(aS1 + k0), (AS3 void*)aD1, 16, 0, 0);
        __builtin_amdgcn_global_load_lds((const AS1 void*)(bS0 + k0), (AS3 void*)bD0, 16, 0, 0);
        __builtin_amdgcn_global_load_lds((const AS1 void*)(bS1 + k0), (AS3 void*)bD1, 16, 0, 0);
        __syncthreads();
        half8 af[4], bf[4];
        #pragma unroll
        for (int mt = 0; mt < 4; mt++)
            af[mt] = *reinterpret_cast<const half8*>(As + (size_t)(wr * 64 + mt * 16 + lr) * 32 + q4 * 8);
        #pragma unroll
        for (int nt = 0; nt < 4; nt++)
            bf[nt] = *reinterpret_cast<const half8*>(Bs + (size_t)(wc * 64 + nt * 16 + lr) * 32 + q4 * 8);
        #pragma unroll
        for (int mt = 0; mt < 4; mt++)
            #pragma unroll
            for (int nt = 0; nt < 4; nt++)
                acc[mt][nt] = MFMA16(af[mt], bf[nt], acc[mt][nt]);
        __syncthreads();
    }

    #pragma unroll
    for (int mt = 0; mt < 4; mt++) {
        #pragma unroll
        for (int nt = 0; nt < 4; nt++) {
            int gn = n0 + wc * 64 + nt * 16 + lr;
            float bval = bias[gn];
            #pragma unroll
            for (int r = 0; r < 4; r++) {
                int gm = m0 + wr * 64 + mt * 16 + q4 * 4 + r;
                out[(size_t)gm * D_ + gn] = acc[mt][nt][r] + bval;
            }
        }
    }
}

extern "C" void kernel_launch(void* const* d_in, const int* in_sizes, int n_in,
                              void* d_out, int out_size, void* d_ws, size_t ws_size,
                              hipStream_t stream) {
    const float* Q_in = (const float*)d_in[0];
    const float* K_in = (const float*)d_in[1];
    const float* V_in = (const float*)d_in[2];
    const float* Wq = (const float*)d_in[3];
    const float* bq = (const float*)d_in[4];
    const float* Wk = (const float*)d_in[5];
    const float* bk = (const float*)d_in[6];
    const float* Wv = (const float*)d_in[7];
    const float* bv = (const float*)d_in[8];
    const float* Wo = (const float*)d_in[9];
    const float* bo = (const float*)d_in[10];

    const size_t NEL = (size_t)B_ * S_ * D_;  // 4M
    _Float16* Xhq = (_Float16*)d_ws;
    _Float16* Xhk = Xhq + NEL;
    _Float16* Xhv = Xhk + NEL;
    _Float16* WqT = Xhv + NEL;
    _Float16* WkT = WqT + (size_t)D_ * D_;
    _Float16* WvT = WkT + (size_t)D_ * D_;
    _Float16* WoT = WvT + (size_t)D_ * D_;
    _Float16* qh  = WoT + (size_t)D_ * D_;
    _Float16* kh  = qh + NEL;
    _Float16* vTh = kh + NEL;
    _Float16* ohh = vTh + NEL;  // out_heads [B,S,D] fp16

    float* out  = (float*)d_out;
    float* attn = out + NEL;  // attn region starts after out [B,S,D]

    const int n4 = (int)(NEL / 4);
    dim3 cvtg((n4 + 255) / 256);
    k_f32_to_f16<<<cvtg, 256, 0, stream>>>(Q_in, Xhq, n4);
    k_f32_to_f16<<<cvtg, 256, 0, stream>>>(K_in, Xhk, n4);
    k_f32_to_f16<<<cvtg, 256, 0, stream>>>(V_in, Xhv, n4);

    k_wtrans<<<dim3(32, 32, 4), dim3(32, 8), 0, stream>>>(Wq, Wk, Wv, Wo, WqT, WkT, WvT, WoT);

    k_qkv_gemm<<<dim3(D_ / 128, (B_ * S_) / 128, 3), 256, 0, stream>>>(
        Xhq, Xhk, Xhv, WqT, WkT, WvT, bq, bk, bv, qh, kh, vTh);

    // dynamic LDS: 16*2048 fp16 (64 KB) + psums[4][16] + invs[16] (fp32)
    const size_t attn_lds = 16 * 2048 * sizeof(_Float16) + 80 * sizeof(float);
    k_attn<<<dim3(S_ / 16, B_ * H_), 256, attn_lds, stream>>>(qh, kh, vTh, attn, ohh);

    k_out_gemm<<<dim3(D_ / 128, (B_ * S_) / 128), 256, 0, stream>>>(ohh, WoT, bo, out);
}